// Round 1
// baseline (3017.519 us; speedup 1.0000x reference)
//
#include <hip/hip_runtime.h>
#include <math.h>

// Problem constants (from reference)
#define BB 4
#define NN 1024
#define EE 1024
#define HH 16
#define DD 64
#define MAXLEN 512
#define EPS 1e-5f

// ---------------------------------------------------------------------------
// LayerNorm: one block (256 threads) per row of E=1024 elements.
// ---------------------------------------------------------------------------
__global__ __launch_bounds__(256) void ln_kernel(const float* __restrict__ x,
                                                 const float* __restrict__ g,
                                                 const float* __restrict__ b,
                                                 float* __restrict__ out) {
    const int row = blockIdx.x;
    const float* xr = x + (size_t)row * EE;
    float s = 0.f, s2 = 0.f;
    for (int j = threadIdx.x; j < EE; j += 256) {
        float v = xr[j];
        s += v; s2 += v * v;
    }
    // wave reduce
    for (int off = 32; off > 0; off >>= 1) {
        s  += __shfl_xor(s, off);
        s2 += __shfl_xor(s2, off);
    }
    __shared__ float red[8];
    const int wave = threadIdx.x >> 6, lane = threadIdx.x & 63;
    if (lane == 0) { red[wave] = s; red[4 + wave] = s2; }
    __syncthreads();
    s  = red[0] + red[1] + red[2] + red[3];
    s2 = red[4] + red[5] + red[6] + red[7];
    const float mu  = s * (1.0f / EE);
    const float var = s2 * (1.0f / EE) - mu * mu;
    const float inv = rsqrtf(var + EPS);
    float* orow = out + (size_t)row * EE;
    for (int j = threadIdx.x; j < EE; j += 256) {
        orow[j] = (xr[j] - mu) * inv * g[j] + b[j];
    }
}

// ---------------------------------------------------------------------------
// Generic tiled fp32 GEMM: C[M,Nc] = A[M,K] @ W[Nc,K]^T + bias (+res) (relu)
// Block: 256 threads computes a 64x64 C tile; K-tile = 16.
// M, Nc divisible by 64; K divisible by 16 (true for all four GEMMs here).
// ---------------------------------------------------------------------------
template <bool RELU, bool HAS_RES>
__global__ __launch_bounds__(256) void gemm_kernel(const float* __restrict__ A,
                                                   const float* __restrict__ W,
                                                   const float* __restrict__ bias,
                                                   const float* __restrict__ res,
                                                   float* __restrict__ C,
                                                   int M, int Nc, int K) {
    __shared__ float As[16][64];
    __shared__ float Bs[16][64];

    const int row0 = blockIdx.y * 64;
    const int col0 = blockIdx.x * 64;
    const int tid = threadIdx.x;
    const int tx = tid & 15;       // 0..15 -> 4 cols each
    const int ty = tid >> 4;       // 0..15 -> 4 rows each

    float acc[4][4];
#pragma unroll
    for (int i = 0; i < 4; ++i)
#pragma unroll
        for (int j = 0; j < 4; ++j) acc[i][j] = 0.f;

    for (int k0 = 0; k0 < K; k0 += 16) {
        // load A tile (64 rows x 16 k) and W tile (64 cols x 16 k)
        for (int idx = tid; idx < 64 * 16; idx += 256) {
            int r = idx >> 4, kk = idx & 15;
            As[kk][r] = A[(size_t)(row0 + r) * K + k0 + kk];
            Bs[kk][r] = W[(size_t)(col0 + r) * K + k0 + kk];
        }
        __syncthreads();
#pragma unroll
        for (int kk = 0; kk < 16; ++kk) {
            float a[4], w[4];
#pragma unroll
            for (int i = 0; i < 4; ++i) a[i] = As[kk][ty * 4 + i];
#pragma unroll
            for (int j = 0; j < 4; ++j) w[j] = Bs[kk][tx * 4 + j];
#pragma unroll
            for (int i = 0; i < 4; ++i)
#pragma unroll
                for (int j = 0; j < 4; ++j) acc[i][j] += a[i] * w[j];
        }
        __syncthreads();
    }

#pragma unroll
    for (int i = 0; i < 4; ++i) {
        const int r = row0 + ty * 4 + i;
#pragma unroll
        for (int j = 0; j < 4; ++j) {
            const int c = col0 + tx * 4 + j;
            float v = acc[i][j] + bias[c];
            if (HAS_RES) v += res[(size_t)r * Nc + c];
            if (RELU) v = fmaxf(v, 0.f);
            C[(size_t)r * Nc + c] = v;
        }
    }
}

// ---------------------------------------------------------------------------
// Attention. rel_bias(i,j) is finite only for 0 <= i-j < 512 (causal sliding
// window). One block per (b, h, 16-row Q tile). Scores for the live window
// (<= 9 chunks of 64 keys) kept in LDS; K/V staged via a shared chunk buffer.
// qkv layout: [B, N, 3E] with q at [0:E], k at [E:2E], v at [2E:3E], head h
// at column offset h*D.
// ---------------------------------------------------------------------------
__global__ __launch_bounds__(256) void attn_kernel(const float* __restrict__ qkv,
                                                   const float* __restrict__ rel_pos,
                                                   float* __restrict__ o) {
    __shared__ float q_s[16][65];
    __shared__ float sc[16][640];
    __shared__ float cs[64][65];
    __shared__ float row_inv[16];

    const int qt = blockIdx.x;          // q tile index (16 rows)
    const int h  = blockIdx.y;
    const int b  = blockIdx.z;
    const int q0 = qt * 16;
    const int tid = threadIdx.x;

    const int jlo = max(0, q0 - (MAXLEN - 1));
    const int jhi = q0 + 15;            // <= N-1
    const int c0 = jlo >> 6;
    const int c1 = jhi >> 6;
    const int jb0 = c0 << 6;
    const int Lloc = (c1 - c0 + 1) << 6;  // <= 576

    const size_t rowstride = 3 * EE;
    const size_t base_q = (size_t)(b * NN) * rowstride + h * DD;
    const size_t base_k = base_q + EE;
    const size_t base_v = base_q + 2 * EE;

    // load + pre-scale Q tile (1/sqrt(64) = 0.125)
    for (int idx = tid; idx < 16 * 64; idx += 256) {
        int i = idx >> 6, d = idx & 63;
        q_s[i][d] = qkv[base_q + (size_t)(q0 + i) * rowstride + d] * 0.125f;
    }
    __syncthreads();

    // ---- scores ----
    for (int c = c0; c <= c1; ++c) {
        const int jb = c << 6;
        for (int idx = tid; idx < 64 * 64; idx += 256) {
            int r = idx >> 6, d = idx & 63;
            cs[r][d] = qkv[base_k + (size_t)(jb + r) * rowstride + d];
        }
        __syncthreads();
#pragma unroll
        for (int p = 0; p < 4; ++p) {
            int idx = p * 256 + tid;
            int i = idx >> 6;           // 0..15
            int r = idx & 63;
            int jg = jb + r;
            int rel = (q0 + i) - jg;
            float s;
            if (rel >= 0 && rel < MAXLEN) {
                float dot = 0.f;
#pragma unroll
                for (int d = 0; d < 64; ++d) dot += q_s[i][d] * cs[r][d];
                s = dot + rel_pos[h * MAXLEN + rel];
            } else {
                s = -INFINITY;
            }
            sc[i][jb - jb0 + r] = s;
        }
        __syncthreads();
    }

    // ---- softmax (each wave handles 4 rows) ----
    {
        const int wave = tid >> 6, lane = tid & 63;
        for (int i = wave; i < 16; i += 4) {
            float m = -INFINITY;
            for (int j = lane; j < Lloc; j += 64) m = fmaxf(m, sc[i][j]);
            for (int off = 32; off > 0; off >>= 1) m = fmaxf(m, __shfl_xor(m, off));
            float ssum = 0.f;
            for (int j = lane; j < Lloc; j += 64) {
                float p = expf(sc[i][j] - m);
                sc[i][j] = p;
                ssum += p;
            }
            for (int off = 32; off > 0; off >>= 1) ssum += __shfl_xor(ssum, off);
            if (lane == 0) row_inv[i] = 1.0f / ssum;
        }
    }
    __syncthreads();

    // ---- P @ V ----
    float acc[4] = {0.f, 0.f, 0.f, 0.f};
    const int d  = tid & 63;
    const int ib = tid >> 6;            // rows ib, ib+4, ib+8, ib+12
    for (int c = c0; c <= c1; ++c) {
        const int jb = c << 6;
        for (int idx = tid; idx < 64 * 64; idx += 256) {
            int r = idx >> 6, dd = idx & 63;
            cs[r][dd] = qkv[base_v + (size_t)(jb + r) * rowstride + dd];
        }
        __syncthreads();
        const int off = jb - jb0;
#pragma unroll 8
        for (int r = 0; r < 64; ++r) {
            float vv = cs[r][d];
            acc[0] += sc[ib][off + r] * vv;
            acc[1] += sc[ib + 4][off + r] * vv;
            acc[2] += sc[ib + 8][off + r] * vv;
            acc[3] += sc[ib + 12][off + r] * vv;
        }
        __syncthreads();
    }
#pragma unroll
    for (int k = 0; k < 4; ++k) {
        const int i = ib + 4 * k;
        o[(size_t)(b * NN + q0 + i) * EE + h * DD + d] = acc[k] * row_inv[i];
    }
}

// ---------------------------------------------------------------------------
// Launch
// ---------------------------------------------------------------------------
extern "C" void kernel_launch(void* const* d_in, const int* in_sizes, int n_in,
                              void* d_out, int out_size, void* d_ws, size_t ws_size,
                              hipStream_t stream) {
    const float* x         = (const float*)d_in[0];
    const float* rel_pos   = (const float*)d_in[1];
    const float* in_proj_w = (const float*)d_in[2];
    const float* in_proj_b = (const float*)d_in[3];
    const float* out_w     = (const float*)d_in[4];
    const float* out_b     = (const float*)d_in[5];
    const float* w1        = (const float*)d_in[6];
    const float* b1        = (const float*)d_in[7];
    const float* w2        = (const float*)d_in[8];
    const float* b2        = (const float*)d_in[9];
    const float* ln1_g     = (const float*)d_in[10];
    const float* ln1_b     = (const float*)d_in[11];
    const float* ln2_g     = (const float*)d_in[12];
    const float* ln2_b     = (const float*)d_in[13];
    float* out = (float*)d_out;
    float* ws  = (float*)d_ws;

    const size_t M4 = (size_t)BB * NN * EE;   // 4M elements
    float* xn   = ws;            // [0, 4M)
    float* qkv  = ws + M4;       // [4M, 16M)
    float* o    = ws + 4 * M4;   // [16M, 20M)
    float* xm   = ws;            // reuse xn after QKV GEMM
    float* hbuf = ws + M4;       // reuse qkv+o region (16M floats) for FFN hidden

    const int Mrows = BB * NN;   // 4096

    // 1) LN1
    ln_kernel<<<Mrows, 256, 0, stream>>>(x, ln1_g, ln1_b, xn);
    // 2) QKV projection: [4096,3072]
    gemm_kernel<false, false><<<dim3(3072 / 64, Mrows / 64), 256, 0, stream>>>(
        xn, in_proj_w, in_proj_b, nullptr, qkv, Mrows, 3 * EE, EE);
    // 3) attention
    attn_kernel<<<dim3(NN / 16, HH, BB), 256, 0, stream>>>(qkv, rel_pos, o);
    // 4) out projection + residual -> x1 (stored in d_out)
    gemm_kernel<false, true><<<dim3(EE / 64, Mrows / 64), 256, 0, stream>>>(
        o, out_w, out_b, x, out, Mrows, EE, EE);
    // 5) LN2
    ln_kernel<<<Mrows, 256, 0, stream>>>(out, ln2_g, ln2_b, xm);
    // 6) FFN1 + ReLU: [4096,4096]
    gemm_kernel<true, false><<<dim3(4 * EE / 64, Mrows / 64), 256, 0, stream>>>(
        xm, w1, b1, nullptr, hbuf, Mrows, 4 * EE, EE);
    // 7) FFN2 + residual (in-place on d_out)
    gemm_kernel<false, true><<<dim3(EE / 64, Mrows / 64), 256, 0, stream>>>(
        hbuf, w2, b2, out, out, Mrows, EE, 4 * EE);
}

// Round 2
// 949.773 us; speedup vs baseline: 3.1771x; 3.1771x over previous
//
#include <hip/hip_runtime.h>
#include <math.h>

// Problem constants (from reference)
#define BB 4
#define NN 1024
#define EE 1024
#define HH 16
#define DD 64
#define MAXLEN 512
#define EPS 1e-5f

typedef __attribute__((ext_vector_type(8))) __bf16 bf16x8;
typedef __attribute__((ext_vector_type(4))) float floatx4;

__device__ __forceinline__ unsigned short f2bf(float f) {
    unsigned u = __float_as_uint(f);
    u += 0x7fffu + ((u >> 16) & 1u);   // RNE
    return (unsigned short)(u >> 16);
}
__device__ __forceinline__ float bf2f(unsigned short h) {
    return __uint_as_float(((unsigned)h) << 16);
}

// ---------------------------------------------------------------------------
// fp32 -> bf16 conversion (vectorized by 4)
// ---------------------------------------------------------------------------
__global__ __launch_bounds__(256) void f2bf_kernel(const float* __restrict__ in,
                                                   unsigned short* __restrict__ out,
                                                   int n4) {
    int i = blockIdx.x * 256 + threadIdx.x;
    if (i < n4) {
        float4 v = ((const float4*)in)[i];
        ushort4 o;
        o.x = f2bf(v.x); o.y = f2bf(v.y); o.z = f2bf(v.z); o.w = f2bf(v.w);
        ((ushort4*)out)[i] = o;
    }
}

// ---------------------------------------------------------------------------
// LayerNorm: one block (256 threads) per row of E=1024; bf16 output.
// ---------------------------------------------------------------------------
__global__ __launch_bounds__(256) void ln_kernel(const float* __restrict__ x,
                                                 const float* __restrict__ g,
                                                 const float* __restrict__ b,
                                                 unsigned short* __restrict__ out) {
    const int row = blockIdx.x;
    const float* xr = x + (size_t)row * EE;
    float s = 0.f, s2 = 0.f;
    for (int j = threadIdx.x; j < EE; j += 256) {
        float v = xr[j];
        s += v; s2 += v * v;
    }
    for (int off = 32; off > 0; off >>= 1) {
        s  += __shfl_xor(s, off);
        s2 += __shfl_xor(s2, off);
    }
    __shared__ float red[8];
    const int wave = threadIdx.x >> 6, lane = threadIdx.x & 63;
    if (lane == 0) { red[wave] = s; red[4 + wave] = s2; }
    __syncthreads();
    s  = red[0] + red[1] + red[2] + red[3];
    s2 = red[4] + red[5] + red[6] + red[7];
    const float mu  = s * (1.0f / EE);
    const float var = s2 * (1.0f / EE) - mu * mu;
    const float inv = rsqrtf(var + EPS);
    unsigned short* orow = out + (size_t)row * EE;
    for (int j = threadIdx.x; j < EE; j += 256) {
        orow[j] = f2bf((xr[j] - mu) * inv * g[j] + b[j]);
    }
}

// ---------------------------------------------------------------------------
// bf16 MFMA GEMM (m97 structure): C[M,Nc] = A[M,K] @ W[Nc,K]^T + bias
// optional +res (fp32), optional relu; output fp32 or bf16.
// Block: 256 thr = 4 waves; 128x128 C tile; BK=32; 16x16x32 bf16 MFMA;
// global_load_lds width-16 staging; two-barrier K-loop.
// Requires M%128==0, Nc%128==0, K%32==0.
// ---------------------------------------------------------------------------
template <bool RELU, bool HAS_RES, bool OUT_BF16>
__global__ __launch_bounds__(256) void gemm_bf16_kernel(
    const unsigned short* __restrict__ A,
    const unsigned short* __restrict__ W,
    const float* __restrict__ bias,
    const float* res, void* Cout, int M, int Nc, int K) {
    __shared__ unsigned short As[128 * 32];
    __shared__ unsigned short Bs[128 * 32];

    const int tid  = threadIdx.x;
    const int lane = tid & 63;
    const int wv   = tid >> 6;
    const int row0 = blockIdx.y * 128;
    const int col0 = blockIdx.x * 128;
    const int waveM = (wv & 1) * 64;
    const int waveN = (wv >> 1) * 64;

    floatx4 acc[4][4];
#pragma unroll
    for (int i = 0; i < 4; ++i)
#pragma unroll
        for (int j = 0; j < 4; ++j) acc[i][j] = (floatx4){0.f, 0.f, 0.f, 0.f};

    const int sr   = wv * 32;          // this wave's staging row base
    const int lrow = lane >> 2;        // 0..15 row within a 16-row issue
    const int lk8  = (lane & 3) * 8;   // element offset within BK=32
    const int frow = lane & 15;
    const int kc8  = (lane >> 4) * 8;

    for (int k0 = 0; k0 < K; k0 += 32) {
#pragma unroll
        for (int q = 0; q < 2; ++q) {
            const int r = sr + q * 16;
            const unsigned short* ga = A + (size_t)(row0 + r + lrow) * K + k0 + lk8;
            const unsigned short* gb = W + (size_t)(col0 + r + lrow) * K + k0 + lk8;
            __builtin_amdgcn_global_load_lds(
                (const __attribute__((address_space(1))) unsigned int*)ga,
                (__attribute__((address_space(3))) unsigned int*)&As[r * 32], 16, 0, 0);
            __builtin_amdgcn_global_load_lds(
                (const __attribute__((address_space(1))) unsigned int*)gb,
                (__attribute__((address_space(3))) unsigned int*)&Bs[r * 32], 16, 0, 0);
        }
        __syncthreads();   // drains vmcnt: tiles resident

        bf16x8 af[4], bfr[4];
#pragma unroll
        for (int t = 0; t < 4; ++t) {
            af[t]  = *(const bf16x8*)&As[(waveM + t * 16 + frow) * 32 + kc8];
            bfr[t] = *(const bf16x8*)&Bs[(waveN + t * 16 + frow) * 32 + kc8];
        }
#pragma unroll
        for (int i = 0; i < 4; ++i)
#pragma unroll
            for (int j = 0; j < 4; ++j)
                acc[i][j] = __builtin_amdgcn_mfma_f32_16x16x32_bf16(
                    af[i], bfr[j], acc[i][j], 0, 0, 0);
        __syncthreads();   // tiles free for overwrite
    }

    // Epilogue: D layout row=(lane>>4)*4+reg, col=lane&15
    float* Cf = (float*)Cout;
    unsigned short* Cb = (unsigned short*)Cout;
    const int crow = (lane >> 4) * 4;
    const int ccol = lane & 15;
#pragma unroll
    for (int j = 0; j < 4; ++j) {
        const int n = col0 + waveN + j * 16 + ccol;
        const float bv = bias[n];
#pragma unroll
        for (int i = 0; i < 4; ++i) {
#pragma unroll
            for (int r = 0; r < 4; ++r) {
                const int m = row0 + waveM + i * 16 + crow + r;
                float v = acc[i][j][r] + bv;
                if (HAS_RES) v += res[(size_t)m * Nc + n];
                if (RELU) v = fmaxf(v, 0.f);
                if (OUT_BF16) Cb[(size_t)m * Nc + n] = f2bf(v);
                else          Cf[(size_t)m * Nc + n] = v;
            }
        }
    }
}

// ---------------------------------------------------------------------------
// Attention (fp32 compute, bf16 qkv in / bf16 o out).
// rel_bias(i,j) finite only for 0 <= i-j < 512 (causal sliding window).
// One block per (b, h, 16-row Q tile).
// ---------------------------------------------------------------------------
__global__ __launch_bounds__(256) void attn_kernel(const unsigned short* __restrict__ qkv,
                                                   const float* __restrict__ rel_pos,
                                                   unsigned short* __restrict__ o) {
    __shared__ float q_s[16][65];
    __shared__ float sc[16][640];
    __shared__ float cs[64][65];
    __shared__ float row_inv[16];

    const int qt = blockIdx.x;
    const int h  = blockIdx.y;
    const int b  = blockIdx.z;
    const int q0 = qt * 16;
    const int tid = threadIdx.x;

    const int jlo = max(0, q0 - (MAXLEN - 1));
    const int jhi = q0 + 15;
    const int c0 = jlo >> 6;
    const int c1 = jhi >> 6;
    const int jb0 = c0 << 6;
    const int Lloc = (c1 - c0 + 1) << 6;

    const size_t rowstride = 3 * EE;
    const size_t base_q = (size_t)(b * NN) * rowstride + h * DD;
    const size_t base_k = base_q + EE;
    const size_t base_v = base_q + 2 * EE;

    for (int idx = tid; idx < 16 * 64; idx += 256) {
        int i = idx >> 6, d = idx & 63;
        q_s[i][d] = bf2f(qkv[base_q + (size_t)(q0 + i) * rowstride + d]) * 0.125f;
    }
    __syncthreads();

    // ---- scores ----
    for (int c = c0; c <= c1; ++c) {
        const int jb = c << 6;
        for (int idx = tid; idx < 64 * 64; idx += 256) {
            int r = idx >> 6, d = idx & 63;
            cs[r][d] = bf2f(qkv[base_k + (size_t)(jb + r) * rowstride + d]);
        }
        __syncthreads();
#pragma unroll
        for (int p = 0; p < 4; ++p) {
            int idx = p * 256 + tid;
            int i = idx >> 6;
            int r = idx & 63;
            int jg = jb + r;
            int rel = (q0 + i) - jg;
            float s;
            if (rel >= 0 && rel < MAXLEN) {
                float dot = 0.f;
#pragma unroll
                for (int d = 0; d < 64; ++d) dot += q_s[i][d] * cs[r][d];
                s = dot + rel_pos[h * MAXLEN + rel];
            } else {
                s = -INFINITY;
            }
            sc[i][jb - jb0 + r] = s;
        }
        __syncthreads();
    }

    // ---- softmax ----
    {
        const int wave = tid >> 6, lane = tid & 63;
        for (int i = wave; i < 16; i += 4) {
            float m = -INFINITY;
            for (int j = lane; j < Lloc; j += 64) m = fmaxf(m, sc[i][j]);
            for (int off = 32; off > 0; off >>= 1) m = fmaxf(m, __shfl_xor(m, off));
            float ssum = 0.f;
            for (int j = lane; j < Lloc; j += 64) {
                float p = expf(sc[i][j] - m);
                sc[i][j] = p;
                ssum += p;
            }
            for (int off = 32; off > 0; off >>= 1) ssum += __shfl_xor(ssum, off);
            if (lane == 0) row_inv[i] = 1.0f / ssum;
        }
    }
    __syncthreads();

    // ---- P @ V ----
    float acc[4] = {0.f, 0.f, 0.f, 0.f};
    const int d  = tid & 63;
    const int ib = tid >> 6;
    for (int c = c0; c <= c1; ++c) {
        const int jb = c << 6;
        for (int idx = tid; idx < 64 * 64; idx += 256) {
            int r = idx >> 6, dd = idx & 63;
            cs[r][dd] = bf2f(qkv[base_v + (size_t)(jb + r) * rowstride + dd]);
        }
        __syncthreads();
        const int off = jb - jb0;
#pragma unroll 8
        for (int r = 0; r < 64; ++r) {
            float vv = cs[r][d];
            acc[0] += sc[ib][off + r] * vv;
            acc[1] += sc[ib + 4][off + r] * vv;
            acc[2] += sc[ib + 8][off + r] * vv;
            acc[3] += sc[ib + 12][off + r] * vv;
        }
        __syncthreads();
    }
#pragma unroll
    for (int k = 0; k < 4; ++k) {
        const int i = ib + 4 * k;
        o[(size_t)(b * NN + q0 + i) * EE + h * DD + d] = f2bf(acc[k] * row_inv[i]);
    }
}

// ---------------------------------------------------------------------------
// Launch
// ---------------------------------------------------------------------------
extern "C" void kernel_launch(void* const* d_in, const int* in_sizes, int n_in,
                              void* d_out, int out_size, void* d_ws, size_t ws_size,
                              hipStream_t stream) {
    const float* x         = (const float*)d_in[0];
    const float* rel_pos   = (const float*)d_in[1];
    const float* in_proj_w = (const float*)d_in[2];
    const float* in_proj_b = (const float*)d_in[3];
    const float* out_w     = (const float*)d_in[4];
    const float* out_b     = (const float*)d_in[5];
    const float* w1        = (const float*)d_in[6];
    const float* b1        = (const float*)d_in[7];
    const float* w2        = (const float*)d_in[8];
    const float* b2        = (const float*)d_in[9];
    const float* ln1_g     = (const float*)d_in[10];
    const float* ln1_b     = (const float*)d_in[11];
    const float* ln2_g     = (const float*)d_in[12];
    const float* ln2_b     = (const float*)d_in[13];
    float* out = (float*)d_out;

    char* wsb = (char*)d_ws;
    const size_t MB = 1024 * 1024;
    unsigned short* wqkv_b = (unsigned short*)(wsb + 0);        // 3M elems, 6 MB
    unsigned short* wout_b = (unsigned short*)(wsb + 6 * MB);   // 1M elems, 2 MB
    unsigned short* w1_b   = (unsigned short*)(wsb + 8 * MB);   // 4M elems, 8 MB
    unsigned short* w2_b   = (unsigned short*)(wsb + 16 * MB);  // 4M elems, 8 MB
    unsigned short* xn_b   = (unsigned short*)(wsb + 24 * MB);  // 4M elems (xn, then xm)
    unsigned short* qkv_b  = (unsigned short*)(wsb + 32 * MB);  // 12M elems, 24 MB
    unsigned short* h_b    = (unsigned short*)(wsb + 32 * MB);  // 16M elems, reuses qkv+o
    unsigned short* o_b    = (unsigned short*)(wsb + 56 * MB);  // 4M elems, 8 MB

    const int Mrows = BB * NN;   // 4096

    // 0) weight conversions (every call: ws is re-poisoned)
    f2bf_kernel<<<(3 * EE * EE / 4 + 255) / 256, 256, 0, stream>>>(in_proj_w, wqkv_b, 3 * EE * EE / 4);
    f2bf_kernel<<<(EE * EE / 4 + 255) / 256, 256, 0, stream>>>(out_w, wout_b, EE * EE / 4);
    f2bf_kernel<<<(4 * EE * EE / 4 + 255) / 256, 256, 0, stream>>>(w1, w1_b, 4 * EE * EE / 4);
    f2bf_kernel<<<(4 * EE * EE / 4 + 255) / 256, 256, 0, stream>>>(w2, w2_b, 4 * EE * EE / 4);

    // 1) LN1 -> bf16
    ln_kernel<<<Mrows, 256, 0, stream>>>(x, ln1_g, ln1_b, xn_b);
    // 2) QKV projection [4096,3072] (bf16 out)
    gemm_bf16_kernel<false, false, true><<<dim3(3072 / 128, Mrows / 128), 256, 0, stream>>>(
        xn_b, wqkv_b, in_proj_b, nullptr, qkv_b, Mrows, 3 * EE, EE);
    // 3) attention (bf16 out)
    attn_kernel<<<dim3(NN / 16, HH, BB), 256, 0, stream>>>(qkv_b, rel_pos, o_b);
    // 4) out projection + residual -> fp32 d_out
    gemm_bf16_kernel<false, true, false><<<dim3(EE / 128, Mrows / 128), 256, 0, stream>>>(
        o_b, wout_b, out_b, x, out, Mrows, EE, EE);
    // 5) LN2 -> bf16
    ln_kernel<<<Mrows, 256, 0, stream>>>(out, ln2_g, ln2_b, xn_b);
    // 6) FFN1 + ReLU [4096,4096] (bf16 out)
    gemm_bf16_kernel<true, false, true><<<dim3(4 * EE / 128, Mrows / 128), 256, 0, stream>>>(
        xn_b, w1_b, b1, nullptr, h_b, Mrows, 4 * EE, EE);
    // 7) FFN2 + residual (fp32, in-place on d_out)
    gemm_bf16_kernel<false, true, false><<<dim3(EE / 128, Mrows / 128), 256, 0, stream>>>(
        h_b, w2_b, b2, out, out, Mrows, EE, 4 * EE);
}

// Round 3
// 416.489 us; speedup vs baseline: 7.2451x; 2.2804x over previous
//
#include <hip/hip_runtime.h>
#include <math.h>

// Problem constants (from reference)
#define BB 4
#define NN 1024
#define EE 1024
#define HH 16
#define DD 64
#define MAXLEN 512
#define EPS 1e-5f

typedef __attribute__((ext_vector_type(8))) __bf16 bf16x8;
typedef __attribute__((ext_vector_type(4))) float floatx4;
typedef __attribute__((ext_vector_type(8))) unsigned short ushort8;

__device__ __forceinline__ unsigned short f2bf(float f) {
    unsigned u = __float_as_uint(f);
    u += 0x7fffu + ((u >> 16) & 1u);   // RNE
    return (unsigned short)(u >> 16);
}
__device__ __forceinline__ float bf2f(unsigned short h) {
    return __uint_as_float(((unsigned)h) << 16);
}

// ---------------------------------------------------------------------------
// fp32 -> bf16 conversion (vectorized by 4)
// ---------------------------------------------------------------------------
__global__ __launch_bounds__(256) void f2bf_kernel(const float* __restrict__ in,
                                                   unsigned short* __restrict__ out,
                                                   int n4) {
    int i = blockIdx.x * 256 + threadIdx.x;
    if (i < n4) {
        float4 v = ((const float4*)in)[i];
        ushort4 o;
        o.x = f2bf(v.x); o.y = f2bf(v.y); o.z = f2bf(v.z); o.w = f2bf(v.w);
        ((ushort4*)out)[i] = o;
    }
}

// ---------------------------------------------------------------------------
// LayerNorm: one block (256 threads) per row of E=1024; bf16 output.
// ---------------------------------------------------------------------------
__global__ __launch_bounds__(256) void ln_kernel(const float* __restrict__ x,
                                                 const float* __restrict__ g,
                                                 const float* __restrict__ b,
                                                 unsigned short* __restrict__ out) {
    const int row = blockIdx.x;
    const float* xr = x + (size_t)row * EE;
    float s = 0.f, s2 = 0.f;
    for (int j = threadIdx.x; j < EE; j += 256) {
        float v = xr[j];
        s += v; s2 += v * v;
    }
    for (int off = 32; off > 0; off >>= 1) {
        s  += __shfl_xor(s, off);
        s2 += __shfl_xor(s2, off);
    }
    __shared__ float red[8];
    const int wave = threadIdx.x >> 6, lane = threadIdx.x & 63;
    if (lane == 0) { red[wave] = s; red[4 + wave] = s2; }
    __syncthreads();
    s  = red[0] + red[1] + red[2] + red[3];
    s2 = red[4] + red[5] + red[6] + red[7];
    const float mu  = s * (1.0f / EE);
    const float var = s2 * (1.0f / EE) - mu * mu;
    const float inv = rsqrtf(var + EPS);
    unsigned short* orow = out + (size_t)row * EE;
    for (int j = threadIdx.x; j < EE; j += 256) {
        orow[j] = f2bf((xr[j] - mu) * inv * g[j] + b[j]);
    }
}

// ---------------------------------------------------------------------------
// bf16 MFMA GEMM (m97 structure): C[M,Nc] = A[M,K] @ W[Nc,K]^T + bias
// ---------------------------------------------------------------------------
template <bool RELU, bool HAS_RES, bool OUT_BF16>
__global__ __launch_bounds__(256) void gemm_bf16_kernel(
    const unsigned short* __restrict__ A,
    const unsigned short* __restrict__ W,
    const float* __restrict__ bias,
    const float* res, void* Cout, int M, int Nc, int K) {
    __shared__ unsigned short As[128 * 32];
    __shared__ unsigned short Bs[128 * 32];

    const int tid  = threadIdx.x;
    const int lane = tid & 63;
    const int wv   = tid >> 6;
    const int row0 = blockIdx.y * 128;
    const int col0 = blockIdx.x * 128;
    const int waveM = (wv & 1) * 64;
    const int waveN = (wv >> 1) * 64;

    floatx4 acc[4][4];
#pragma unroll
    for (int i = 0; i < 4; ++i)
#pragma unroll
        for (int j = 0; j < 4; ++j) acc[i][j] = (floatx4){0.f, 0.f, 0.f, 0.f};

    const int sr   = wv * 32;
    const int lrow = lane >> 2;
    const int lk8  = (lane & 3) * 8;
    const int frow = lane & 15;
    const int kc8  = (lane >> 4) * 8;

    for (int k0 = 0; k0 < K; k0 += 32) {
#pragma unroll
        for (int q = 0; q < 2; ++q) {
            const int r = sr + q * 16;
            const unsigned short* ga = A + (size_t)(row0 + r + lrow) * K + k0 + lk8;
            const unsigned short* gb = W + (size_t)(col0 + r + lrow) * K + k0 + lk8;
            __builtin_amdgcn_global_load_lds(
                (const __attribute__((address_space(1))) unsigned int*)ga,
                (__attribute__((address_space(3))) unsigned int*)&As[r * 32], 16, 0, 0);
            __builtin_amdgcn_global_load_lds(
                (const __attribute__((address_space(1))) unsigned int*)gb,
                (__attribute__((address_space(3))) unsigned int*)&Bs[r * 32], 16, 0, 0);
        }
        __syncthreads();

        bf16x8 af[4], bfr[4];
#pragma unroll
        for (int t = 0; t < 4; ++t) {
            af[t]  = *(const bf16x8*)&As[(waveM + t * 16 + frow) * 32 + kc8];
            bfr[t] = *(const bf16x8*)&Bs[(waveN + t * 16 + frow) * 32 + kc8];
        }
#pragma unroll
        for (int i = 0; i < 4; ++i)
#pragma unroll
            for (int j = 0; j < 4; ++j)
                acc[i][j] = __builtin_amdgcn_mfma_f32_16x16x32_bf16(
                    af[i], bfr[j], acc[i][j], 0, 0, 0);
        __syncthreads();
    }

    float* Cf = (float*)Cout;
    unsigned short* Cb = (unsigned short*)Cout;
    const int crow = (lane >> 4) * 4;
    const int ccol = lane & 15;
#pragma unroll
    for (int j = 0; j < 4; ++j) {
        const int n = col0 + waveN + j * 16 + ccol;
        const float bv = bias[n];
#pragma unroll
        for (int i = 0; i < 4; ++i) {
#pragma unroll
            for (int r = 0; r < 4; ++r) {
                const int m = row0 + waveM + i * 16 + crow + r;
                float v = acc[i][j][r] + bv;
                if (HAS_RES) v += res[(size_t)m * Nc + n];
                if (RELU) v = fmaxf(v, 0.f);
                if (OUT_BF16) Cb[(size_t)m * Nc + n] = f2bf(v);
                else          Cf[(size_t)m * Nc + n] = v;
            }
        }
    }
}

// ---------------------------------------------------------------------------
// Flash-style MFMA attention. rel_bias(i,j) finite only for 0 <= i-j < 512
// (causal sliding window). One block = 64 Q rows for (b,h); 4 waves, each
// owns 16 Q rows. QK^T and PV via mfma_f32_16x16x32_bf16; online softmax.
// K staged [ks][key][32] (m97 conflict-free pitch) via global_load_lds;
// V staged transposed [d][key] pitch 72; P round-trips LDS (C->A layout).
// ---------------------------------------------------------------------------
__global__ __launch_bounds__(256) void attn_mfma_kernel(
    const unsigned short* __restrict__ qkv,
    const float* __restrict__ rel_pos,
    unsigned short* __restrict__ o) {
    __shared__ unsigned short K_s[2][64][32];     // 8 KB
    __shared__ unsigned short V_s[64][72];        // 9 KB  [d][key]
    __shared__ unsigned short P_s[4][2][16][32];  // 8 KB  per-wave
    __shared__ float rel_s[MAXLEN];               // 2 KB

    const int qt = blockIdx.x, h = blockIdx.y, b = blockIdx.z;
    const int q0 = qt * 64;
    const int tid  = threadIdx.x;
    const int lane = tid & 63;
    const int w    = tid >> 6;
    const int quad = lane >> 4;
    const int c15  = lane & 15;

    rel_s[tid]       = rel_pos[h * MAXLEN + tid];
    rel_s[tid + 256] = rel_pos[h * MAXLEN + tid + 256];

    const size_t rowstride = 3 * EE;
    const size_t base_q = (size_t)(b * NN) * rowstride + h * DD;
    const size_t base_k = base_q + EE;
    const size_t base_v = base_q + 2 * EE;

    // Q fragments (A layout): m = c15 within wave tile, k = ks*32 + quad*8 + j
    bf16x8 aq[2];
    {
        const unsigned short* qrow =
            qkv + base_q + (size_t)(q0 + w * 16 + c15) * rowstride + quad * 8;
        aq[0] = *(const bf16x8*)(qrow);
        aq[1] = *(const bf16x8*)(qrow + 32);
    }

    floatx4 Oacc[4];
#pragma unroll
    for (int j = 0; j < 4; ++j) Oacc[j] = (floatx4){0.f, 0.f, 0.f, 0.f};
    float m_r[4], l_r[4];
#pragma unroll
    for (int r = 0; r < 4; ++r) { m_r[r] = -1e30f; l_r[r] = 0.f; }

    const int jlo = max(0, q0 - (MAXLEN - 1));
    const int c0 = jlo >> 6;
    const int c1 = (q0 + 63) >> 6;

    for (int cc = c0; cc <= c1; ++cc) {
        const int jb0 = cc << 6;
        __syncthreads();   // prior iteration's readers done (also covers rel_s)

        // ---- stage K (global_load_lds, wave w covers rows w*16..w*16+15) ----
        {
            const int krow = w * 16 + (lane >> 2);
            const int dofs = (lane & 3) * 8;
            const unsigned short* gk =
                qkv + base_k + (size_t)(jb0 + krow) * rowstride + dofs;
            __builtin_amdgcn_global_load_lds(
                (const __attribute__((address_space(1))) unsigned int*)gk,
                (__attribute__((address_space(3))) unsigned int*)&K_s[0][w * 16][0],
                16, 0, 0);
            __builtin_amdgcn_global_load_lds(
                (const __attribute__((address_space(1))) unsigned int*)(gk + 32),
                (__attribute__((address_space(3))) unsigned int*)&K_s[1][w * 16][0],
                16, 0, 0);
        }
        // ---- stage V transposed: thread reads V[key][d0..d0+15] ----
        {
            const int key = lane;
            const int d0  = w * 16;
            const unsigned short* gv =
                qkv + base_v + (size_t)(jb0 + key) * rowstride + d0;
            ushort8 va = *(const ushort8*)(gv);
            ushort8 vb = *(const ushort8*)(gv + 8);
#pragma unroll
            for (int ii = 0; ii < 8; ++ii) V_s[d0 + ii][key] = va[ii];
#pragma unroll
            for (int ii = 0; ii < 8; ++ii) V_s[d0 + 8 + ii][key] = vb[ii];
        }
        __syncthreads();   // tiles resident (drains vmcnt for global_load_lds)

        // ---- S = Q K^T (16 x 64), C-layout: row = quad*4 + r, col = c15 ----
        floatx4 S[4];
#pragma unroll
        for (int jb = 0; jb < 4; ++jb) {
            S[jb] = (floatx4){0.f, 0.f, 0.f, 0.f};
            bf16x8 bk0 = *(const bf16x8*)&K_s[0][jb * 16 + c15][quad * 8];
            bf16x8 bk1 = *(const bf16x8*)&K_s[1][jb * 16 + c15][quad * 8];
            S[jb] = __builtin_amdgcn_mfma_f32_16x16x32_bf16(aq[0], bk0, S[jb], 0, 0, 0);
            S[jb] = __builtin_amdgcn_mfma_f32_16x16x32_bf16(aq[1], bk1, S[jb], 0, 0, 0);
        }

        // ---- bias + mask + online softmax ----
        const int i_base = q0 + w * 16 + quad * 4;
        float sv[4][4];
        float mc[4] = {-1e30f, -1e30f, -1e30f, -1e30f};
#pragma unroll
        for (int jb = 0; jb < 4; ++jb) {
            const int jg = jb0 + jb * 16 + c15;
#pragma unroll
            for (int r = 0; r < 4; ++r) {
                const int rel = (i_base + r) - jg;
                float s;
                if (rel >= 0 && rel < MAXLEN) s = S[jb][r] * 0.125f + rel_s[rel];
                else                          s = -1e30f;
                sv[jb][r] = s;
                mc[r] = fmaxf(mc[r], s);
            }
        }
#pragma unroll
        for (int off = 1; off < 16; off <<= 1)
#pragma unroll
            for (int r = 0; r < 4; ++r) mc[r] = fmaxf(mc[r], __shfl_xor(mc[r], off));

        float alpha[4], psum[4];
#pragma unroll
        for (int r = 0; r < 4; ++r) {
            const float mn = fmaxf(m_r[r], mc[r]);
            alpha[r] = __expf(m_r[r] - mn);
            m_r[r] = mn;
            psum[r] = 0.f;
        }
#pragma unroll
        for (int jb = 0; jb < 4; ++jb)
#pragma unroll
            for (int r = 0; r < 4; ++r) {
                const float p = __expf(sv[jb][r] - m_r[r]);
                sv[jb][r] = p;
                psum[r] += p;
            }
#pragma unroll
        for (int off = 1; off < 16; off <<= 1)
#pragma unroll
            for (int r = 0; r < 4; ++r) psum[r] += __shfl_xor(psum[r], off);
#pragma unroll
        for (int r = 0; r < 4; ++r) l_r[r] = l_r[r] * alpha[r] + psum[r];
#pragma unroll
        for (int jb = 0; jb < 4; ++jb)
#pragma unroll
            for (int r = 0; r < 4; ++r) Oacc[jb][r] *= alpha[r];

        // ---- P: C-layout regs -> LDS [ks][row][key'] (A-layout readback) ----
#pragma unroll
        for (int jb = 0; jb < 4; ++jb)
#pragma unroll
            for (int r = 0; r < 4; ++r)
                P_s[w][jb >> 1][quad * 4 + r][(jb & 1) * 16 + c15] = f2bf(sv[jb][r]);

        bf16x8 ap0 = *(const bf16x8*)&P_s[w][0][c15][quad * 8];
        bf16x8 ap1 = *(const bf16x8*)&P_s[w][1][c15][quad * 8];

        // ---- O += P V ----
#pragma unroll
        for (int jd = 0; jd < 4; ++jd) {
            bf16x8 bv0 = *(const bf16x8*)&V_s[jd * 16 + c15][quad * 8];
            bf16x8 bv1 = *(const bf16x8*)&V_s[jd * 16 + c15][32 + quad * 8];
            Oacc[jd] = __builtin_amdgcn_mfma_f32_16x16x32_bf16(ap0, bv0, Oacc[jd], 0, 0, 0);
            Oacc[jd] = __builtin_amdgcn_mfma_f32_16x16x32_bf16(ap1, bv1, Oacc[jd], 0, 0, 0);
        }
    }

    // ---- epilogue ----
    float inv[4];
#pragma unroll
    for (int r = 0; r < 4; ++r) inv[r] = 1.0f / l_r[r];
#pragma unroll
    for (int jd = 0; jd < 4; ++jd) {
#pragma unroll
        for (int r = 0; r < 4; ++r) {
            const int row = q0 + w * 16 + quad * 4 + r;
            const int col = h * DD + jd * 16 + c15;
            o[(size_t)(b * NN + row) * EE + col] = f2bf(Oacc[jd][r] * inv[r]);
        }
    }
}

// ---------------------------------------------------------------------------
// Launch
// ---------------------------------------------------------------------------
extern "C" void kernel_launch(void* const* d_in, const int* in_sizes, int n_in,
                              void* d_out, int out_size, void* d_ws, size_t ws_size,
                              hipStream_t stream) {
    const float* x         = (const float*)d_in[0];
    const float* rel_pos   = (const float*)d_in[1];
    const float* in_proj_w = (const float*)d_in[2];
    const float* in_proj_b = (const float*)d_in[3];
    const float* out_w     = (const float*)d_in[4];
    const float* out_b     = (const float*)d_in[5];
    const float* w1        = (const float*)d_in[6];
    const float* b1        = (const float*)d_in[7];
    const float* w2        = (const float*)d_in[8];
    const float* b2        = (const float*)d_in[9];
    const float* ln1_g     = (const float*)d_in[10];
    const float* ln1_b     = (const float*)d_in[11];
    const float* ln2_g     = (const float*)d_in[12];
    const float* ln2_b     = (const float*)d_in[13];
    float* out = (float*)d_out;

    char* wsb = (char*)d_ws;
    const size_t MB = 1024 * 1024;
    unsigned short* wqkv_b = (unsigned short*)(wsb + 0);        // 6 MB
    unsigned short* wout_b = (unsigned short*)(wsb + 6 * MB);   // 2 MB
    unsigned short* w1_b   = (unsigned short*)(wsb + 8 * MB);   // 8 MB
    unsigned short* w2_b   = (unsigned short*)(wsb + 16 * MB);  // 8 MB
    unsigned short* xn_b   = (unsigned short*)(wsb + 24 * MB);  // 8 MB (xn, then xm)
    unsigned short* qkv_b  = (unsigned short*)(wsb + 32 * MB);  // 24 MB
    unsigned short* h_b    = (unsigned short*)(wsb + 32 * MB);  // 32 MB (reuses qkv+o)
    unsigned short* o_b    = (unsigned short*)(wsb + 56 * MB);  // 8 MB

    const int Mrows = BB * NN;   // 4096

    f2bf_kernel<<<(3 * EE * EE / 4 + 255) / 256, 256, 0, stream>>>(in_proj_w, wqkv_b, 3 * EE * EE / 4);
    f2bf_kernel<<<(EE * EE / 4 + 255) / 256, 256, 0, stream>>>(out_w, wout_b, EE * EE / 4);
    f2bf_kernel<<<(4 * EE * EE / 4 + 255) / 256, 256, 0, stream>>>(w1, w1_b, 4 * EE * EE / 4);
    f2bf_kernel<<<(4 * EE * EE / 4 + 255) / 256, 256, 0, stream>>>(w2, w2_b, 4 * EE * EE / 4);

    ln_kernel<<<Mrows, 256, 0, stream>>>(x, ln1_g, ln1_b, xn_b);
    gemm_bf16_kernel<false, false, true><<<dim3(3072 / 128, Mrows / 128), 256, 0, stream>>>(
        xn_b, wqkv_b, in_proj_b, nullptr, qkv_b, Mrows, 3 * EE, EE);
    attn_mfma_kernel<<<dim3(NN / 64, HH, BB), 256, 0, stream>>>(qkv_b, rel_pos, o_b);
    gemm_bf16_kernel<false, true, false><<<dim3(EE / 128, Mrows / 128), 256, 0, stream>>>(
        o_b, wout_b, out_b, x, out, Mrows, EE, EE);
    ln_kernel<<<Mrows, 256, 0, stream>>>(out, ln2_g, ln2_b, xn_b);
    gemm_bf16_kernel<true, false, true><<<dim3(4 * EE / 128, Mrows / 128), 256, 0, stream>>>(
        xn_b, w1_b, b1, nullptr, h_b, Mrows, 4 * EE, EE);
    gemm_bf16_kernel<false, true, false><<<dim3(EE / 128, Mrows / 128), 256, 0, stream>>>(
        h_b, w2_b, b2, out, out, Mrows, EE, 4 * EE);
}

// Round 4
// 390.355 us; speedup vs baseline: 7.7302x; 1.0669x over previous
//
#include <hip/hip_runtime.h>
#include <math.h>

// Problem constants (from reference)
#define BB 4
#define NN 1024
#define EE 1024
#define HH 16
#define DD 64
#define MAXLEN 512
#define EPS 1e-5f

typedef __attribute__((ext_vector_type(8))) __bf16 bf16x8;
typedef __attribute__((ext_vector_type(4))) float floatx4;
typedef __attribute__((ext_vector_type(8))) unsigned short ushort8;

__device__ __forceinline__ unsigned short f2bf(float f) {
    unsigned u = __float_as_uint(f);
    u += 0x7fffu + ((u >> 16) & 1u);   // RNE
    return (unsigned short)(u >> 16);
}
__device__ __forceinline__ float bf2f(unsigned short h) {
    return __uint_as_float(((unsigned)h) << 16);
}

// ---------------------------------------------------------------------------
// fp32 -> bf16 conversion (vectorized by 4)
// ---------------------------------------------------------------------------
__global__ __launch_bounds__(256) void f2bf_kernel(const float* __restrict__ in,
                                                   unsigned short* __restrict__ out,
                                                   int n4) {
    int i = blockIdx.x * 256 + threadIdx.x;
    if (i < n4) {
        float4 v = ((const float4*)in)[i];
        ushort4 o;
        o.x = f2bf(v.x); o.y = f2bf(v.y); o.z = f2bf(v.z); o.w = f2bf(v.w);
        ((ushort4*)out)[i] = o;
    }
}

// ---------------------------------------------------------------------------
// LayerNorm: one block (256 threads) per row of E=1024; bf16 output.
// ---------------------------------------------------------------------------
__global__ __launch_bounds__(256) void ln_kernel(const float* __restrict__ x,
                                                 const float* __restrict__ g,
                                                 const float* __restrict__ b,
                                                 unsigned short* __restrict__ out) {
    const int row = blockIdx.x;
    const float* xr = x + (size_t)row * EE;
    float s = 0.f, s2 = 0.f;
    for (int j = threadIdx.x; j < EE; j += 256) {
        float v = xr[j];
        s += v; s2 += v * v;
    }
    for (int off = 32; off > 0; off >>= 1) {
        s  += __shfl_xor(s, off);
        s2 += __shfl_xor(s2, off);
    }
    __shared__ float red[8];
    const int wave = threadIdx.x >> 6, lane = threadIdx.x & 63;
    if (lane == 0) { red[wave] = s; red[4 + wave] = s2; }
    __syncthreads();
    s  = red[0] + red[1] + red[2] + red[3];
    s2 = red[4] + red[5] + red[6] + red[7];
    const float mu  = s * (1.0f / EE);
    const float var = s2 * (1.0f / EE) - mu * mu;
    const float inv = rsqrtf(var + EPS);
    unsigned short* orow = out + (size_t)row * EE;
    for (int j = threadIdx.x; j < EE; j += 256) {
        orow[j] = f2bf((xr[j] - mu) * inv * g[j] + b[j]);
    }
}

// ---------------------------------------------------------------------------
// bf16 MFMA GEMM (m97 structure): C[M,Nc] = A[M,K] @ W[Nc,K]^T + bias
// Tile: 128 x TN (TN = 128 or 64). TN=64 doubles the grid for N-starved
// shapes (N=1024 -> 512 blocks = 2 blocks/CU instead of 1).
// ---------------------------------------------------------------------------
template <int TN, bool RELU, bool HAS_RES, bool OUT_BF16>
__global__ __launch_bounds__(256) void gemm_bf16_kernel(
    const unsigned short* __restrict__ A,
    const unsigned short* __restrict__ W,
    const float* __restrict__ bias,
    const float* res, void* Cout, int M, int Nc, int K) {
    constexpr int WN = TN / 2;       // wave N extent: 64 or 32
    constexpr int NJ = WN / 16;      // N frags per wave: 4 or 2
    constexpr int BI = TN / 64;      // B staging issues per wave: 2 or 1
    __shared__ unsigned short As[128 * 32];
    __shared__ unsigned short Bs[TN * 32];

    const int tid  = threadIdx.x;
    const int lane = tid & 63;
    const int wv   = tid >> 6;
    const int row0 = blockIdx.y * 128;
    const int col0 = blockIdx.x * TN;
    const int waveM = (wv & 1) * 64;
    const int waveN = (wv >> 1) * WN;

    floatx4 acc[4][NJ];
#pragma unroll
    for (int i = 0; i < 4; ++i)
#pragma unroll
        for (int j = 0; j < NJ; ++j) acc[i][j] = (floatx4){0.f, 0.f, 0.f, 0.f};

    const int lrow = lane >> 2;
    const int lk8  = (lane & 3) * 8;
    const int frow = lane & 15;
    const int kc8  = (lane >> 4) * 8;

    for (int k0 = 0; k0 < K; k0 += 32) {
#pragma unroll
        for (int q = 0; q < 2; ++q) {
            const int r = wv * 32 + q * 16;
            const unsigned short* ga = A + (size_t)(row0 + r + lrow) * K + k0 + lk8;
            __builtin_amdgcn_global_load_lds(
                (const __attribute__((address_space(1))) unsigned int*)ga,
                (__attribute__((address_space(3))) unsigned int*)&As[r * 32], 16, 0, 0);
        }
#pragma unroll
        for (int q = 0; q < BI; ++q) {
            const int r = wv * (16 * BI) + q * 16;
            const unsigned short* gb = W + (size_t)(col0 + r + lrow) * K + k0 + lk8;
            __builtin_amdgcn_global_load_lds(
                (const __attribute__((address_space(1))) unsigned int*)gb,
                (__attribute__((address_space(3))) unsigned int*)&Bs[r * 32], 16, 0, 0);
        }
        __syncthreads();

        bf16x8 af[4], bfr[NJ];
#pragma unroll
        for (int t = 0; t < 4; ++t)
            af[t] = *(const bf16x8*)&As[(waveM + t * 16 + frow) * 32 + kc8];
#pragma unroll
        for (int t = 0; t < NJ; ++t)
            bfr[t] = *(const bf16x8*)&Bs[(waveN + t * 16 + frow) * 32 + kc8];
#pragma unroll
        for (int i = 0; i < 4; ++i)
#pragma unroll
            for (int j = 0; j < NJ; ++j)
                acc[i][j] = __builtin_amdgcn_mfma_f32_16x16x32_bf16(
                    af[i], bfr[j], acc[i][j], 0, 0, 0);
        __syncthreads();
    }

    float* Cf = (float*)Cout;
    unsigned short* Cb = (unsigned short*)Cout;
    const int crow = (lane >> 4) * 4;
    const int ccol = lane & 15;
#pragma unroll
    for (int j = 0; j < NJ; ++j) {
        const int n = col0 + waveN + j * 16 + ccol;
        const float bv = bias[n];
#pragma unroll
        for (int i = 0; i < 4; ++i) {
#pragma unroll
            for (int r = 0; r < 4; ++r) {
                const int m = row0 + waveM + i * 16 + crow + r;
                float v = acc[i][j][r] + bv;
                if (HAS_RES) v += res[(size_t)m * Nc + n];
                if (RELU) v = fmaxf(v, 0.f);
                if (OUT_BF16) Cb[(size_t)m * Nc + n] = f2bf(v);
                else          Cf[(size_t)m * Nc + n] = v;
            }
        }
    }
}

// ---------------------------------------------------------------------------
// Flash-style MFMA attention. rel_bias(i,j) finite only for 0 <= i-j < 512
// (causal sliding window). One block = 64 Q rows for (b,h); 4 waves, each
// owns 16 Q rows. QK^T and PV via mfma_f32_16x16x32_bf16; online softmax.
// ---------------------------------------------------------------------------
__global__ __launch_bounds__(256) void attn_mfma_kernel(
    const unsigned short* __restrict__ qkv,
    const float* __restrict__ rel_pos,
    unsigned short* __restrict__ o) {
    __shared__ unsigned short K_s[2][64][32];     // 8 KB
    __shared__ unsigned short V_s[64][72];        // 9 KB  [d][key]
    __shared__ unsigned short P_s[4][2][16][32];  // 8 KB  per-wave
    __shared__ float rel_s[MAXLEN];               // 2 KB

    const int qt = blockIdx.x, h = blockIdx.y, b = blockIdx.z;
    const int q0 = qt * 64;
    const int tid  = threadIdx.x;
    const int lane = tid & 63;
    const int w    = tid >> 6;
    const int quad = lane >> 4;
    const int c15  = lane & 15;

    rel_s[tid]       = rel_pos[h * MAXLEN + tid];
    rel_s[tid + 256] = rel_pos[h * MAXLEN + tid + 256];

    const size_t rowstride = 3 * EE;
    const size_t base_q = (size_t)(b * NN) * rowstride + h * DD;
    const size_t base_k = base_q + EE;
    const size_t base_v = base_q + 2 * EE;

    bf16x8 aq[2];
    {
        const unsigned short* qrow =
            qkv + base_q + (size_t)(q0 + w * 16 + c15) * rowstride + quad * 8;
        aq[0] = *(const bf16x8*)(qrow);
        aq[1] = *(const bf16x8*)(qrow + 32);
    }

    floatx4 Oacc[4];
#pragma unroll
    for (int j = 0; j < 4; ++j) Oacc[j] = (floatx4){0.f, 0.f, 0.f, 0.f};
    float m_r[4], l_r[4];
#pragma unroll
    for (int r = 0; r < 4; ++r) { m_r[r] = -1e30f; l_r[r] = 0.f; }

    const int jlo = max(0, q0 - (MAXLEN - 1));
    const int c0 = jlo >> 6;
    const int c1 = (q0 + 63) >> 6;

    for (int cc = c0; cc <= c1; ++cc) {
        const int jb0 = cc << 6;
        __syncthreads();

        {
            const int krow = w * 16 + (lane >> 2);
            const int dofs = (lane & 3) * 8;
            const unsigned short* gk =
                qkv + base_k + (size_t)(jb0 + krow) * rowstride + dofs;
            __builtin_amdgcn_global_load_lds(
                (const __attribute__((address_space(1))) unsigned int*)gk,
                (__attribute__((address_space(3))) unsigned int*)&K_s[0][w * 16][0],
                16, 0, 0);
            __builtin_amdgcn_global_load_lds(
                (const __attribute__((address_space(1))) unsigned int*)(gk + 32),
                (__attribute__((address_space(3))) unsigned int*)&K_s[1][w * 16][0],
                16, 0, 0);
        }
        {
            const int key = lane;
            const int d0  = w * 16;
            const unsigned short* gv =
                qkv + base_v + (size_t)(jb0 + key) * rowstride + d0;
            ushort8 va = *(const ushort8*)(gv);
            ushort8 vb = *(const ushort8*)(gv + 8);
#pragma unroll
            for (int ii = 0; ii < 8; ++ii) V_s[d0 + ii][key] = va[ii];
#pragma unroll
            for (int ii = 0; ii < 8; ++ii) V_s[d0 + 8 + ii][key] = vb[ii];
        }
        __syncthreads();

        floatx4 S[4];
#pragma unroll
        for (int jb = 0; jb < 4; ++jb) {
            S[jb] = (floatx4){0.f, 0.f, 0.f, 0.f};
            bf16x8 bk0 = *(const bf16x8*)&K_s[0][jb * 16 + c15][quad * 8];
            bf16x8 bk1 = *(const bf16x8*)&K_s[1][jb * 16 + c15][quad * 8];
            S[jb] = __builtin_amdgcn_mfma_f32_16x16x32_bf16(aq[0], bk0, S[jb], 0, 0, 0);
            S[jb] = __builtin_amdgcn_mfma_f32_16x16x32_bf16(aq[1], bk1, S[jb], 0, 0, 0);
        }

        const int i_base = q0 + w * 16 + quad * 4;
        float sv[4][4];
        float mc[4] = {-1e30f, -1e30f, -1e30f, -1e30f};
#pragma unroll
        for (int jb = 0; jb < 4; ++jb) {
            const int jg = jb0 + jb * 16 + c15;
#pragma unroll
            for (int r = 0; r < 4; ++r) {
                const int rel = (i_base + r) - jg;
                float s;
                if (rel >= 0 && rel < MAXLEN) s = S[jb][r] * 0.125f + rel_s[rel];
                else                          s = -1e30f;
                sv[jb][r] = s;
                mc[r] = fmaxf(mc[r], s);
            }
        }
#pragma unroll
        for (int off = 1; off < 16; off <<= 1)
#pragma unroll
            for (int r = 0; r < 4; ++r) mc[r] = fmaxf(mc[r], __shfl_xor(mc[r], off));

        float alpha[4], psum[4];
#pragma unroll
        for (int r = 0; r < 4; ++r) {
            const float mn = fmaxf(m_r[r], mc[r]);
            alpha[r] = __expf(m_r[r] - mn);
            m_r[r] = mn;
            psum[r] = 0.f;
        }
#pragma unroll
        for (int jb = 0; jb < 4; ++jb)
#pragma unroll
            for (int r = 0; r < 4; ++r) {
                const float p = __expf(sv[jb][r] - m_r[r]);
                sv[jb][r] = p;
                psum[r] += p;
            }
#pragma unroll
        for (int off = 1; off < 16; off <<= 1)
#pragma unroll
            for (int r = 0; r < 4; ++r) psum[r] += __shfl_xor(psum[r], off);
#pragma unroll
        for (int r = 0; r < 4; ++r) l_r[r] = l_r[r] * alpha[r] + psum[r];
#pragma unroll
        for (int jb = 0; jb < 4; ++jb)
#pragma unroll
            for (int r = 0; r < 4; ++r) Oacc[jb][r] *= alpha[r];

#pragma unroll
        for (int jb = 0; jb < 4; ++jb)
#pragma unroll
            for (int r = 0; r < 4; ++r)
                P_s[w][jb >> 1][quad * 4 + r][(jb & 1) * 16 + c15] = f2bf(sv[jb][r]);

        bf16x8 ap0 = *(const bf16x8*)&P_s[w][0][c15][quad * 8];
        bf16x8 ap1 = *(const bf16x8*)&P_s[w][1][c15][quad * 8];

#pragma unroll
        for (int jd = 0; jd < 4; ++jd) {
            bf16x8 bv0 = *(const bf16x8*)&V_s[jd * 16 + c15][quad * 8];
            bf16x8 bv1 = *(const bf16x8*)&V_s[jd * 16 + c15][32 + quad * 8];
            Oacc[jd] = __builtin_amdgcn_mfma_f32_16x16x32_bf16(ap0, bv0, Oacc[jd], 0, 0, 0);
            Oacc[jd] = __builtin_amdgcn_mfma_f32_16x16x32_bf16(ap1, bv1, Oacc[jd], 0, 0, 0);
        }
    }

    float inv[4];
#pragma unroll
    for (int r = 0; r < 4; ++r) inv[r] = 1.0f / l_r[r];
#pragma unroll
    for (int jd = 0; jd < 4; ++jd) {
#pragma unroll
        for (int r = 0; r < 4; ++r) {
            const int row = q0 + w * 16 + quad * 4 + r;
            const int col = h * DD + jd * 16 + c15;
            o[(size_t)(b * NN + row) * EE + col] = f2bf(Oacc[jd][r] * inv[r]);
        }
    }
}

// ---------------------------------------------------------------------------
// Launch
// ---------------------------------------------------------------------------
extern "C" void kernel_launch(void* const* d_in, const int* in_sizes, int n_in,
                              void* d_out, int out_size, void* d_ws, size_t ws_size,
                              hipStream_t stream) {
    const float* x         = (const float*)d_in[0];
    const float* rel_pos   = (const float*)d_in[1];
    const float* in_proj_w = (const float*)d_in[2];
    const float* in_proj_b = (const float*)d_in[3];
    const float* out_w     = (const float*)d_in[4];
    const float* out_b     = (const float*)d_in[5];
    const float* w1        = (const float*)d_in[6];
    const float* b1        = (const float*)d_in[7];
    const float* w2        = (const float*)d_in[8];
    const float* b2        = (const float*)d_in[9];
    const float* ln1_g     = (const float*)d_in[10];
    const float* ln1_b     = (const float*)d_in[11];
    const float* ln2_g     = (const float*)d_in[12];
    const float* ln2_b     = (const float*)d_in[13];
    float* out = (float*)d_out;

    char* wsb = (char*)d_ws;
    const size_t MB = 1024 * 1024;
    unsigned short* wqkv_b = (unsigned short*)(wsb + 0);        // 6 MB
    unsigned short* wout_b = (unsigned short*)(wsb + 6 * MB);   // 2 MB
    unsigned short* w1_b   = (unsigned short*)(wsb + 8 * MB);   // 8 MB
    unsigned short* w2_b   = (unsigned short*)(wsb + 16 * MB);  // 8 MB
    unsigned short* xn_b   = (unsigned short*)(wsb + 24 * MB);  // 8 MB (xn, then xm)
    unsigned short* qkv_b  = (unsigned short*)(wsb + 32 * MB);  // 24 MB
    unsigned short* h_b    = (unsigned short*)(wsb + 32 * MB);  // 32 MB (reuses qkv+o)
    unsigned short* o_b    = (unsigned short*)(wsb + 56 * MB);  // 8 MB

    const int Mrows = BB * NN;   // 4096

    f2bf_kernel<<<(3 * EE * EE / 4 + 255) / 256, 256, 0, stream>>>(in_proj_w, wqkv_b, 3 * EE * EE / 4);
    f2bf_kernel<<<(EE * EE / 4 + 255) / 256, 256, 0, stream>>>(out_w, wout_b, EE * EE / 4);
    f2bf_kernel<<<(4 * EE * EE / 4 + 255) / 256, 256, 0, stream>>>(w1, w1_b, 4 * EE * EE / 4);
    f2bf_kernel<<<(4 * EE * EE / 4 + 255) / 256, 256, 0, stream>>>(w2, w2_b, 4 * EE * EE / 4);

    ln_kernel<<<Mrows, 256, 0, stream>>>(x, ln1_g, ln1_b, xn_b);
    // QKV: N=3072 -> 24x32 = 768 blocks with TN=128 (3/CU): keep 128x128
    gemm_bf16_kernel<128, false, false, true><<<dim3(3072 / 128, Mrows / 128), 256, 0, stream>>>(
        xn_b, wqkv_b, in_proj_b, nullptr, qkv_b, Mrows, 3 * EE, EE);
    attn_mfma_kernel<<<dim3(NN / 64, HH, BB), 256, 0, stream>>>(qkv_b, rel_pos, o_b);
    // out-proj: N=1024 -> TN=64 gives 16x32 = 512 blocks (2/CU)
    gemm_bf16_kernel<64, false, true, false><<<dim3(EE / 64, Mrows / 128), 256, 0, stream>>>(
        o_b, wout_b, out_b, x, out, Mrows, EE, EE);
    ln_kernel<<<Mrows, 256, 0, stream>>>(out, ln2_g, ln2_b, xn_b);
    // FFN1: N=4096 -> 32x32 = 1024 blocks with TN=128 (4/CU): keep 128x128
    gemm_bf16_kernel<128, true, false, true><<<dim3(4 * EE / 128, Mrows / 128), 256, 0, stream>>>(
        xn_b, w1_b, b1, nullptr, h_b, Mrows, 4 * EE, EE);
    // FFN2: N=1024 -> TN=64 gives 512 blocks (2/CU)
    gemm_bf16_kernel<64, false, true, false><<<dim3(EE / 64, Mrows / 128), 256, 0, stream>>>(
        h_b, w2_b, b2, out, out, Mrows, EE, 4 * EE);
}

// Round 5
// 376.061 us; speedup vs baseline: 8.0240x; 1.0380x over previous
//
#include <hip/hip_runtime.h>
#include <math.h>

// Problem constants (from reference)
#define BB 4
#define NN 1024
#define EE 1024
#define HH 16
#define DD 64
#define MAXLEN 512
#define EPS 1e-5f

typedef __attribute__((ext_vector_type(8))) __bf16 bf16x8;
typedef __attribute__((ext_vector_type(4))) float floatx4;
typedef __attribute__((ext_vector_type(8))) unsigned short ushort8;

__device__ __forceinline__ unsigned short f2bf(float f) {
    unsigned u = __float_as_uint(f);
    u += 0x7fffu + ((u >> 16) & 1u);   // RNE
    return (unsigned short)(u >> 16);
}
__device__ __forceinline__ float bf2f(unsigned short h) {
    return __uint_as_float(((unsigned)h) << 16);
}

// ---------------------------------------------------------------------------
// fp32 -> bf16 conversion (vectorized by 4)
// ---------------------------------------------------------------------------
__global__ __launch_bounds__(256) void f2bf_kernel(const float* __restrict__ in,
                                                   unsigned short* __restrict__ out,
                                                   int n4) {
    int i = blockIdx.x * 256 + threadIdx.x;
    if (i < n4) {
        float4 v = ((const float4*)in)[i];
        ushort4 o;
        o.x = f2bf(v.x); o.y = f2bf(v.y); o.z = f2bf(v.z); o.w = f2bf(v.w);
        ((ushort4*)out)[i] = o;
    }
}

// ---------------------------------------------------------------------------
// LayerNorm: one block (256 threads) per row of E=1024; bf16 output.
// ---------------------------------------------------------------------------
__global__ __launch_bounds__(256) void ln_kernel(const float* __restrict__ x,
                                                 const float* __restrict__ g,
                                                 const float* __restrict__ b,
                                                 unsigned short* __restrict__ out) {
    const int row = blockIdx.x;
    const float* xr = x + (size_t)row * EE;
    float s = 0.f, s2 = 0.f;
    for (int j = threadIdx.x; j < EE; j += 256) {
        float v = xr[j];
        s += v; s2 += v * v;
    }
    for (int off = 32; off > 0; off >>= 1) {
        s  += __shfl_xor(s, off);
        s2 += __shfl_xor(s2, off);
    }
    __shared__ float red[8];
    const int wave = threadIdx.x >> 6, lane = threadIdx.x & 63;
    if (lane == 0) { red[wave] = s; red[4 + wave] = s2; }
    __syncthreads();
    s  = red[0] + red[1] + red[2] + red[3];
    s2 = red[4] + red[5] + red[6] + red[7];
    const float mu  = s * (1.0f / EE);
    const float var = s2 * (1.0f / EE) - mu * mu;
    const float inv = rsqrtf(var + EPS);
    unsigned short* orow = out + (size_t)row * EE;
    for (int j = threadIdx.x; j < EE; j += 256) {
        orow[j] = f2bf((xr[j] - mu) * inv * g[j] + b[j]);
    }
}

// ---------------------------------------------------------------------------
// bf16 MFMA GEMM: C[M,Nc] = A[M,K] @ W[Nc,K]^T + bias (+res) (relu)
// Tile: 128 x TN (TN = 128 or 64). BK=64 per iteration, staged as TWO
// 32-wide sub-tiles in separate LDS regions (keeps the conflict-free
// 64-B-pitch global_load_lds layout) -> ONE barrier pair per 64 K instead
// of two. Requires M%128==0, Nc%TN==0, K%64==0.
// ---------------------------------------------------------------------------
template <int TN, bool RELU, bool HAS_RES, bool OUT_BF16>
__global__ __launch_bounds__(256) void gemm_bf16_kernel(
    const unsigned short* __restrict__ A,
    const unsigned short* __restrict__ W,
    const float* __restrict__ bias,
    const float* res, void* Cout, int M, int Nc, int K) {
    constexpr int WN = TN / 2;       // wave N extent: 64 or 32
    constexpr int NJ = WN / 16;      // N frags per wave: 4 or 2
    constexpr int BI = TN / 64;      // B staging issues per wave per subtile
    __shared__ unsigned short As[2][128 * 32];
    __shared__ unsigned short Bs[2][TN * 32];

    const int tid  = threadIdx.x;
    const int lane = tid & 63;
    const int wv   = tid >> 6;
    const int row0 = blockIdx.y * 128;
    const int col0 = blockIdx.x * TN;
    const int waveM = (wv & 1) * 64;
    const int waveN = (wv >> 1) * WN;

    floatx4 acc[4][NJ];
#pragma unroll
    for (int i = 0; i < 4; ++i)
#pragma unroll
        for (int j = 0; j < NJ; ++j) acc[i][j] = (floatx4){0.f, 0.f, 0.f, 0.f};

    const int lrow = lane >> 2;        // staging: lane covers row lrow, 8 elems
    const int lk8  = (lane & 3) * 8;
    const int frow = lane & 15;        // fragment row
    const int kc8  = (lane >> 4) * 8;  // fragment k offset

    for (int k0 = 0; k0 < K; k0 += 64) {
#pragma unroll
        for (int s = 0; s < 2; ++s) {
            const int kk = k0 + s * 32;
#pragma unroll
            for (int q = 0; q < 2; ++q) {
                const int r = wv * 32 + q * 16;
                const unsigned short* ga = A + (size_t)(row0 + r + lrow) * K + kk + lk8;
                __builtin_amdgcn_global_load_lds(
                    (const __attribute__((address_space(1))) unsigned int*)ga,
                    (__attribute__((address_space(3))) unsigned int*)&As[s][r * 32], 16, 0, 0);
            }
#pragma unroll
            for (int q = 0; q < BI; ++q) {
                const int r = wv * (16 * BI) + q * 16;
                const unsigned short* gb = W + (size_t)(col0 + r + lrow) * K + kk + lk8;
                __builtin_amdgcn_global_load_lds(
                    (const __attribute__((address_space(1))) unsigned int*)gb,
                    (__attribute__((address_space(3))) unsigned int*)&Bs[s][r * 32], 16, 0, 0);
            }
        }
        __syncthreads();   // both sub-tiles resident

#pragma unroll
        for (int s = 0; s < 2; ++s) {
            bf16x8 af[4], bfr[NJ];
#pragma unroll
            for (int t = 0; t < 4; ++t)
                af[t] = *(const bf16x8*)&As[s][(waveM + t * 16 + frow) * 32 + kc8];
#pragma unroll
            for (int t = 0; t < NJ; ++t)
                bfr[t] = *(const bf16x8*)&Bs[s][(waveN + t * 16 + frow) * 32 + kc8];
#pragma unroll
            for (int i = 0; i < 4; ++i)
#pragma unroll
                for (int j = 0; j < NJ; ++j)
                    acc[i][j] = __builtin_amdgcn_mfma_f32_16x16x32_bf16(
                        af[i], bfr[j], acc[i][j], 0, 0, 0);
        }
        __syncthreads();   // tiles free for overwrite
    }

    float* Cf = (float*)Cout;
    unsigned short* Cb = (unsigned short*)Cout;
    const int crow = (lane >> 4) * 4;
    const int ccol = lane & 15;
#pragma unroll
    for (int j = 0; j < NJ; ++j) {
        const int n = col0 + waveN + j * 16 + ccol;
        const float bv = bias[n];
#pragma unroll
        for (int i = 0; i < 4; ++i) {
#pragma unroll
            for (int r = 0; r < 4; ++r) {
                const int m = row0 + waveM + i * 16 + crow + r;
                float v = acc[i][j][r] + bv;
                if (HAS_RES) v += res[(size_t)m * Nc + n];
                if (RELU) v = fmaxf(v, 0.f);
                if (OUT_BF16) Cb[(size_t)m * Nc + n] = f2bf(v);
                else          Cf[(size_t)m * Nc + n] = v;
            }
        }
    }
}

// ---------------------------------------------------------------------------
// Flash-style MFMA attention. rel_bias(i,j) finite only for 0 <= i-j < 512
// (causal sliding window). One block = 64 Q rows for (b,h); 4 waves, each
// owns 16 Q rows. QK^T and PV via mfma_f32_16x16x32_bf16; online softmax.
// ---------------------------------------------------------------------------
__global__ __launch_bounds__(256) void attn_mfma_kernel(
    const unsigned short* __restrict__ qkv,
    const float* __restrict__ rel_pos,
    unsigned short* __restrict__ o) {
    __shared__ unsigned short K_s[2][64][32];     // 8 KB
    __shared__ unsigned short V_s[64][72];        // 9 KB  [d][key]
    __shared__ unsigned short P_s[4][2][16][32];  // 8 KB  per-wave
    __shared__ float rel_s[MAXLEN];               // 2 KB

    const int qt = blockIdx.x, h = blockIdx.y, b = blockIdx.z;
    const int q0 = qt * 64;
    const int tid  = threadIdx.x;
    const int lane = tid & 63;
    const int w    = tid >> 6;
    const int quad = lane >> 4;
    const int c15  = lane & 15;

    rel_s[tid]       = rel_pos[h * MAXLEN + tid];
    rel_s[tid + 256] = rel_pos[h * MAXLEN + tid + 256];

    const size_t rowstride = 3 * EE;
    const size_t base_q = (size_t)(b * NN) * rowstride + h * DD;
    const size_t base_k = base_q + EE;
    const size_t base_v = base_q + 2 * EE;

    bf16x8 aq[2];
    {
        const unsigned short* qrow =
            qkv + base_q + (size_t)(q0 + w * 16 + c15) * rowstride + quad * 8;
        aq[0] = *(const bf16x8*)(qrow);
        aq[1] = *(const bf16x8*)(qrow + 32);
    }

    floatx4 Oacc[4];
#pragma unroll
    for (int j = 0; j < 4; ++j) Oacc[j] = (floatx4){0.f, 0.f, 0.f, 0.f};
    float m_r[4], l_r[4];
#pragma unroll
    for (int r = 0; r < 4; ++r) { m_r[r] = -1e30f; l_r[r] = 0.f; }

    const int jlo = max(0, q0 - (MAXLEN - 1));
    const int c0 = jlo >> 6;
    const int c1 = (q0 + 63) >> 6;

    for (int cc = c0; cc <= c1; ++cc) {
        const int jb0 = cc << 6;
        __syncthreads();

        {
            const int krow = w * 16 + (lane >> 2);
            const int dofs = (lane & 3) * 8;
            const unsigned short* gk =
                qkv + base_k + (size_t)(jb0 + krow) * rowstride + dofs;
            __builtin_amdgcn_global_load_lds(
                (const __attribute__((address_space(1))) unsigned int*)gk,
                (__attribute__((address_space(3))) unsigned int*)&K_s[0][w * 16][0],
                16, 0, 0);
            __builtin_amdgcn_global_load_lds(
                (const __attribute__((address_space(1))) unsigned int*)(gk + 32),
                (__attribute__((address_space(3))) unsigned int*)&K_s[1][w * 16][0],
                16, 0, 0);
        }
        {
            const int key = lane;
            const int d0  = w * 16;
            const unsigned short* gv =
                qkv + base_v + (size_t)(jb0 + key) * rowstride + d0;
            ushort8 va = *(const ushort8*)(gv);
            ushort8 vb = *(const ushort8*)(gv + 8);
#pragma unroll
            for (int ii = 0; ii < 8; ++ii) V_s[d0 + ii][key] = va[ii];
#pragma unroll
            for (int ii = 0; ii < 8; ++ii) V_s[d0 + 8 + ii][key] = vb[ii];
        }
        __syncthreads();

        floatx4 S[4];
#pragma unroll
        for (int jb = 0; jb < 4; ++jb) {
            S[jb] = (floatx4){0.f, 0.f, 0.f, 0.f};
            bf16x8 bk0 = *(const bf16x8*)&K_s[0][jb * 16 + c15][quad * 8];
            bf16x8 bk1 = *(const bf16x8*)&K_s[1][jb * 16 + c15][quad * 8];
            S[jb] = __builtin_amdgcn_mfma_f32_16x16x32_bf16(aq[0], bk0, S[jb], 0, 0, 0);
            S[jb] = __builtin_amdgcn_mfma_f32_16x16x32_bf16(aq[1], bk1, S[jb], 0, 0, 0);
        }

        const int i_base = q0 + w * 16 + quad * 4;
        float sv[4][4];
        float mc[4] = {-1e30f, -1e30f, -1e30f, -1e30f};
#pragma unroll
        for (int jb = 0; jb < 4; ++jb) {
            const int jg = jb0 + jb * 16 + c15;
#pragma unroll
            for (int r = 0; r < 4; ++r) {
                const int rel = (i_base + r) - jg;
                float s;
                if (rel >= 0 && rel < MAXLEN) s = S[jb][r] * 0.125f + rel_s[rel];
                else                          s = -1e30f;
                sv[jb][r] = s;
                mc[r] = fmaxf(mc[r], s);
            }
        }
#pragma unroll
        for (int off = 1; off < 16; off <<= 1)
#pragma unroll
            for (int r = 0; r < 4; ++r) mc[r] = fmaxf(mc[r], __shfl_xor(mc[r], off));

        float alpha[4], psum[4];
#pragma unroll
        for (int r = 0; r < 4; ++r) {
            const float mn = fmaxf(m_r[r], mc[r]);
            alpha[r] = __expf(m_r[r] - mn);
            m_r[r] = mn;
            psum[r] = 0.f;
        }
#pragma unroll
        for (int jb = 0; jb < 4; ++jb)
#pragma unroll
            for (int r = 0; r < 4; ++r) {
                const float p = __expf(sv[jb][r] - m_r[r]);
                sv[jb][r] = p;
                psum[r] += p;
            }
#pragma unroll
        for (int off = 1; off < 16; off <<= 1)
#pragma unroll
            for (int r = 0; r < 4; ++r) psum[r] += __shfl_xor(psum[r], off);
#pragma unroll
        for (int r = 0; r < 4; ++r) l_r[r] = l_r[r] * alpha[r] + psum[r];
#pragma unroll
        for (int jb = 0; jb < 4; ++jb)
#pragma unroll
            for (int r = 0; r < 4; ++r) Oacc[jb][r] *= alpha[r];

#pragma unroll
        for (int jb = 0; jb < 4; ++jb)
#pragma unroll
            for (int r = 0; r < 4; ++r)
                P_s[w][jb >> 1][quad * 4 + r][(jb & 1) * 16 + c15] = f2bf(sv[jb][r]);

        bf16x8 ap0 = *(const bf16x8*)&P_s[w][0][c15][quad * 8];
        bf16x8 ap1 = *(const bf16x8*)&P_s[w][1][c15][quad * 8];

#pragma unroll
        for (int jd = 0; jd < 4; ++jd) {
            bf16x8 bv0 = *(const bf16x8*)&V_s[jd * 16 + c15][quad * 8];
            bf16x8 bv1 = *(const bf16x8*)&V_s[jd * 16 + c15][32 + quad * 8];
            Oacc[jd] = __builtin_amdgcn_mfma_f32_16x16x32_bf16(ap0, bv0, Oacc[jd], 0, 0, 0);
            Oacc[jd] = __builtin_amdgcn_mfma_f32_16x16x32_bf16(ap1, bv1, Oacc[jd], 0, 0, 0);
        }
    }

    float inv[4];
#pragma unroll
    for (int r = 0; r < 4; ++r) inv[r] = 1.0f / l_r[r];
#pragma unroll
    for (int jd = 0; jd < 4; ++jd) {
#pragma unroll
        for (int r = 0; r < 4; ++r) {
            const int row = q0 + w * 16 + quad * 4 + r;
            const int col = h * DD + jd * 16 + c15;
            o[(size_t)(b * NN + row) * EE + col] = f2bf(Oacc[jd][r] * inv[r]);
        }
    }
}

// ---------------------------------------------------------------------------
// Launch
// ---------------------------------------------------------------------------
extern "C" void kernel_launch(void* const* d_in, const int* in_sizes, int n_in,
                              void* d_out, int out_size, void* d_ws, size_t ws_size,
                              hipStream_t stream) {
    const float* x         = (const float*)d_in[0];
    const float* rel_pos   = (const float*)d_in[1];
    const float* in_proj_w = (const float*)d_in[2];
    const float* in_proj_b = (const float*)d_in[3];
    const float* out_w     = (const float*)d_in[4];
    const float* out_b     = (const float*)d_in[5];
    const float* w1        = (const float*)d_in[6];
    const float* b1        = (const float*)d_in[7];
    const float* w2        = (const float*)d_in[8];
    const float* b2        = (const float*)d_in[9];
    const float* ln1_g     = (const float*)d_in[10];
    const float* ln1_b     = (const float*)d_in[11];
    const float* ln2_g     = (const float*)d_in[12];
    const float* ln2_b     = (const float*)d_in[13];
    float* out = (float*)d_out;

    char* wsb = (char*)d_ws;
    const size_t MB = 1024 * 1024;
    unsigned short* wqkv_b = (unsigned short*)(wsb + 0);        // 6 MB
    unsigned short* wout_b = (unsigned short*)(wsb + 6 * MB);   // 2 MB
    unsigned short* w1_b   = (unsigned short*)(wsb + 8 * MB);   // 8 MB
    unsigned short* w2_b   = (unsigned short*)(wsb + 16 * MB);  // 8 MB
    unsigned short* xn_b   = (unsigned short*)(wsb + 24 * MB);  // 8 MB (xn, then xm)
    unsigned short* qkv_b  = (unsigned short*)(wsb + 32 * MB);  // 24 MB
    unsigned short* h_b    = (unsigned short*)(wsb + 32 * MB);  // 32 MB (reuses qkv+o)
    unsigned short* o_b    = (unsigned short*)(wsb + 56 * MB);  // 8 MB

    const int Mrows = BB * NN;   // 4096

    f2bf_kernel<<<(3 * EE * EE / 4 + 255) / 256, 256, 0, stream>>>(in_proj_w, wqkv_b, 3 * EE * EE / 4);
    f2bf_kernel<<<(EE * EE / 4 + 255) / 256, 256, 0, stream>>>(out_w, wout_b, EE * EE / 4);
    f2bf_kernel<<<(4 * EE * EE / 4 + 255) / 256, 256, 0, stream>>>(w1, w1_b, 4 * EE * EE / 4);
    f2bf_kernel<<<(4 * EE * EE / 4 + 255) / 256, 256, 0, stream>>>(w2, w2_b, 4 * EE * EE / 4);

    ln_kernel<<<Mrows, 256, 0, stream>>>(x, ln1_g, ln1_b, xn_b);
    // QKV: N=3072, TN=128 -> 768 blocks (3/CU)
    gemm_bf16_kernel<128, false, false, true><<<dim3(3072 / 128, Mrows / 128), 256, 0, stream>>>(
        xn_b, wqkv_b, in_proj_b, nullptr, qkv_b, Mrows, 3 * EE, EE);
    attn_mfma_kernel<<<dim3(NN / 64, HH, BB), 256, 0, stream>>>(qkv_b, rel_pos, o_b);
    // out-proj: N=1024, TN=64 -> 512 blocks (2/CU)
    gemm_bf16_kernel<64, false, true, false><<<dim3(EE / 64, Mrows / 128), 256, 0, stream>>>(
        o_b, wout_b, out_b, x, out, Mrows, EE, EE);
    ln_kernel<<<Mrows, 256, 0, stream>>>(out, ln2_g, ln2_b, xn_b);
    // FFN1: N=4096, TN=128 -> 1024 blocks (4/CU)
    gemm_bf16_kernel<128, true, false, true><<<dim3(4 * EE / 128, Mrows / 128), 256, 0, stream>>>(
        xn_b, w1_b, b1, nullptr, h_b, Mrows, 4 * EE, EE);
    // FFN2: N=1024, TN=64 -> 512 blocks (2/CU)
    gemm_bf16_kernel<64, false, true, false><<<dim3(EE / 64, Mrows / 128), 256, 0, stream>>>(
        h_b, w2_b, b2, out, out, Mrows, EE, 4 * EE);
}